// Round 3
// baseline (164.447 us; speedup 1.0000x reference)
//
#include <hip/hip_runtime.h>
#include <hip/hip_bf16.h>

namespace {
constexpr int N_ = 4, H_ = 512, W_ = 512, K_ = 4;
constexpr int F_ = 200000;
constexpr float SIGMA_ = 1e-4f;
constexpr float GAMMA_ = 1e-4f;
constexpr float EPS_   = 1e-10f;
constexpr float ZNEAR_ = 1.0f, ZFAR_ = 100.0f;

constexpr int P_ = N_ * H_ * W_;                     // 1,048,576 pixels
constexpr int SHADER_BLOCKS  = 1024;
constexpr int SHADER_THREADS = SHADER_BLOCKS * 256;  // 262,144
constexpr int ITERS = P_ / SHADER_THREADS;           // 4 pixels/thread
static_assert(P_ % SHADER_THREADS == 0, "grid must tile P exactly");

typedef float        f32x4 __attribute__((ext_vector_type(4), aligned(4)));
typedef int          i32x4 __attribute__((ext_vector_type(4), aligned(4)));
typedef float        f32x3 __attribute__((ext_vector_type(3), aligned(4)));
typedef unsigned int u32x4 __attribute__((ext_vector_type(4), aligned(16)));

struct PixIn { i32x4 f4; f32x4 dv, zv, bA, bB, bC; };
} // namespace

// R13 post-mortem of R12: phase reshuffles inside a ONE-SHOT kernel don't
// matter. Counters said: hbm 21%, VALU 24%, occupancy 35% — every pipe idle.
// 2048 blocks = exactly one wave-generation; each wave does loads -> wait ->
// compute -> exit, so memory and VALU phases serialize device-wide (perfect
// overlap would be ~16us; measured 44.6). Fix: software-pipelined grid-stride
// loop (1024 blocks, 4 px/thread): iteration i+1's streaming loads are issued
// during iteration i's compute; gather addresses consume a ptf value loaded a
// full iteration earlier (zero exposed wait). Memory system stays busy during
// VALU and vice versa. launch_bounds(256,4) caps VGPR at 128 to hold 16
// waves/CU residency.

__device__ __forceinline__ unsigned int oct_encode(float x, float y, float z) {
    const float inv = 1.0f / (fabsf(x) + fabsf(y) + fabsf(z)); // unit input
    const float px = x * inv, py = y * inv, pz = z * inv;
    // Standard octahedral wrap for the z<0 hemisphere: (1-|p.yx|)*sign(p.xy)
    const float wx = (1.0f - fabsf(py)) * copysignf(1.0f, px);
    const float wy = (1.0f - fabsf(px)) * copysignf(1.0f, py);
    const bool neg = pz < 0.0f;
    const float ex = neg ? wx : px;
    const float ey = neg ? wy : py;
    const int ix = (int)rintf(ex * 32767.0f);
    const int iy = (int)rintf(ey * 32767.0f);
    return ((unsigned int)ix & 0xffffu) | (((unsigned int)iy & 0xffffu) << 16);
}

// Raw decode: unnormalized vector + reciprocal norm (normalization folded
// into the blend scale by the caller).
__device__ __forceinline__ void oct_decode_raw(unsigned int e,
                                               float& x, float& y, float& z,
                                               float& inv) {
    const float fx = (float)(short)(unsigned short)(e & 0xffffu) * (1.0f / 32767.0f);
    const float fy = (float)(short)(unsigned short)(e >> 16)     * (1.0f / 32767.0f);
    z = 1.0f - fabsf(fx) - fabsf(fy);
    const float t = fmaxf(-z, 0.0f);
    const float xx = fx - copysignf(t, fx);
    const float yy = fy - copysignf(t, fy);
    x = xx; y = yy;
    inv = rsqrtf(xx * xx + yy * yy + z * z);   // argument > 0 for all inputs
}

// K1: fnorm row f (16B): {oct16(n0), oct16(n1), oct16(n2), pad} — written via
// two 8B agent-scope relaxed atomics (write-through; no dirty XCD-L2 lines).
__global__ __launch_bounds__(256) void build_fnorm_kernel(
    const float*  __restrict__ vnorm,
    const int*    __restrict__ faces,
    unsigned int* __restrict__ fnorm)   // [F][4] u32
{
    const int f = blockIdx.x * blockDim.x + threadIdx.x;
    if (f >= F_) return;
    // 16B read covers the 12B face row (4B overread stays in the page).
    const i32x4 fv = *reinterpret_cast<const i32x4*>(faces + 3 * (size_t)f);
    const f32x4 n0 = *reinterpret_cast<const f32x4*>(vnorm + 3 * (size_t)fv.x);
    const f32x4 n1 = *reinterpret_cast<const f32x4*>(vnorm + 3 * (size_t)fv.y);
    const f32x4 n2 = *reinterpret_cast<const f32x4*>(vnorm + 3 * (size_t)fv.z);
    const unsigned long long e0 = oct_encode(n0.x, n0.y, n0.z);
    const unsigned long long e1 = oct_encode(n1.x, n1.y, n1.z);
    const unsigned long long e2 = oct_encode(n2.x, n2.y, n2.z);
    unsigned long long* dst =
        reinterpret_cast<unsigned long long*>(fnorm + (size_t)f * 4);
    __hip_atomic_store(dst + 0, e0 | (e1 << 32), __ATOMIC_RELAXED, __HIP_MEMORY_SCOPE_AGENT);
    __hip_atomic_store(dst + 1, e2,              __ATOMIC_RELAXED, __HIP_MEMORY_SCOPE_AGENT);
}

__device__ __forceinline__ PixIn load_pix(const int*   __restrict__ ptf,
                                          const float* __restrict__ dists,
                                          const float* __restrict__ zbuf,
                                          const float* __restrict__ bary,
                                          int p) {
    PixIn s;
    s.f4 = __builtin_nontemporal_load(reinterpret_cast<const i32x4*>(ptf) + p);
    s.dv = __builtin_nontemporal_load(reinterpret_cast<const f32x4*>(dists) + p);
    s.zv = __builtin_nontemporal_load(reinterpret_cast<const f32x4*>(zbuf) + p);
    const f32x4* bp = reinterpret_cast<const f32x4*>(bary + (size_t)p * 12);
    s.bA = __builtin_nontemporal_load(bp + 0);
    s.bB = __builtin_nontemporal_load(bp + 1);
    s.bC = __builtin_nontemporal_load(bp + 2);
    return s;
}

// K2: software-pipelined grid-stride. Per iteration: gathers (addresses from
// the PREVIOUS iteration's ptf — already in registers) -> issue next
// iteration's 6 streaming loads -> weight exp-chain (data arrived an
// iteration ago) -> decode+blend+store.
__global__ __launch_bounds__(256, 4) void normal_shader_kernel(
    const unsigned int* __restrict__ fnorm,
    const float*        __restrict__ bary,
    const float*        __restrict__ dists,
    const float*        __restrict__ zbuf,
    const int*          __restrict__ ptf,
    float*              __restrict__ out)
{
    const int tid = blockIdx.x * 256 + threadIdx.x;

    // Pipeline prologue: iteration 0's streaming loads.
    PixIn cur = load_pix(ptf, dists, zbuf, bary, tid);

#pragma unroll
    for (int it = 0; it < ITERS; ++it) {
        const int p = tid + it * SHADER_THREADS;
        const int fidx[4] = {cur.f4.x, cur.f4.y, cur.f4.z, cur.f4.w};

        // ---- table gathers: addresses ready (ptf returned >=1 iter ago) ----
        u32x4 row[4];
#pragma unroll
        for (int k = 0; k < K_; ++k) {
            const int r = (fidx[k] < 0) ? 0 : fidx[k];   // only -1 is illegal;
            row[k] = reinterpret_cast<const u32x4*>(fnorm)[r]; // w==0 kills dead slots
        }

        // ---- issue NEXT iteration's streaming loads (overlap everything) ----
        PixIn nxt = cur;                      // dummy init on last iteration
        if (it + 1 < ITERS)
            nxt = load_pix(ptf, dists, zbuf, bary, p + SHADER_THREADS);

        // ---- weights (cur.dv/zv arrived >=1 iteration ago) ----
        const float d[4] = {cur.dv.x, cur.dv.y, cur.dv.z, cur.dv.w};
        const float z[4] = {cur.zv.x, cur.zv.y, cur.zv.z, cur.zv.w};
        float prob[4], zinv[4], zmax = EPS_;
#pragma unroll
        for (int k = 0; k < K_; ++k) {
            const bool valid = fidx[k] >= 0;
            prob[k] = valid ? 1.0f / (1.0f + __expf(d[k] * (1.0f / SIGMA_))) : 0.0f;
            zinv[k] = valid ? (ZFAR_ - z[k]) * (1.0f / (ZFAR_ - ZNEAR_)) : 0.0f;
            zmax = fmaxf(zmax, zinv[k]);
        }
        const float delta = fmaxf(__expf((EPS_ - zmax) * (1.0f / GAMMA_)), EPS_);
        float wn[4];
#pragma unroll
        for (int k = 0; k < K_; ++k)
            wn[k] = prob[k] * __expf((zinv[k] - zmax) * (1.0f / GAMMA_));

        // ---- decode + blend + store ----
        const float bb[12] = {cur.bA.x, cur.bA.y, cur.bA.z, cur.bA.w,
                              cur.bB.x, cur.bB.y, cur.bB.z, cur.bB.w,
                              cur.bC.x, cur.bC.y, cur.bC.z, cur.bC.w};
        float acc0 = 0.f, acc1 = 0.f, acc2 = 0.f, wsum = 0.f;
#pragma unroll
        for (int k = 0; k < K_; ++k) {
            const float w = wn[k];
            wsum += w;
            float x0, y0, z0, i0, x1, y1, z1, i1, x2, y2, z2, i2;
            oct_decode_raw(row[k].x, x0, y0, z0, i0);
            oct_decode_raw(row[k].y, x1, y1, z1, i1);
            oct_decode_raw(row[k].z, x2, y2, z2, i2);
            // fold w * b * (1/|v|) into one scale per normal
            const float s0 = (w * bb[3 * k + 0]) * i0;
            const float s1 = (w * bb[3 * k + 1]) * i1;
            const float s2 = (w * bb[3 * k + 2]) * i2;
            acc0 += s0 * x0 + s1 * x1 + s2 * x2;
            acc1 += s0 * y0 + s1 * y1 + s2 * y2;
            acc2 += s0 * z0 + s1 * z1 + s2 * z2;
        }
        const float inv_denom = 1.0f / (wsum + delta);
        const float r0 = (acc0 + delta) * inv_denom;   // bg = (1,1,1)
        const float r1 = (acc1 + delta) * inv_denom;
        const float r2 = (acc2 + delta) * inv_denom;
        const float nrm = fmaxf(sqrtf(r0 * r0 + r1 * r1 + r2 * r2), 1e-12f);
        const float inv = 1.0f / nrm;
        __builtin_nontemporal_store(
            f32x3{r0 * inv, r1 * inv, r2 * inv},
            reinterpret_cast<f32x3*>(out + (size_t)p * 3));

        cur = nxt;
    }
}

// Fallback (proven R5 structure, exact fp32 path) if ws can't hold the table.
__global__ __launch_bounds__(256) void normal_shader_fused_kernel(
    const float* __restrict__ vnorm,
    const float* __restrict__ bary,
    const float* __restrict__ dists,
    const float* __restrict__ zbuf,
    const int*   __restrict__ faces,
    const int*   __restrict__ ptf,
    float*       __restrict__ out,
    int P)
{
    const int p = blockIdx.x * blockDim.x + threadIdx.x;
    if (p >= P) return;
    const i32x4 f4 = reinterpret_cast<const i32x4*>(ptf)[p];
    const int fidx[4] = {f4.x, f4.y, f4.z, f4.w};
    const f32x4 dv = reinterpret_cast<const f32x4*>(dists)[p];
    const f32x4 zv = reinterpret_cast<const f32x4*>(zbuf)[p];
    const float d[4] = {dv.x, dv.y, dv.z, dv.w};
    const float z[4] = {zv.x, zv.y, zv.z, zv.w};
    float prob[4], zinv[4], zmax = EPS_;
#pragma unroll
    for (int k = 0; k < K_; ++k) {
        const bool valid = fidx[k] >= 0;
        prob[k] = valid ? 1.0f / (1.0f + __expf(d[k] * (1.0f / SIGMA_))) : 0.0f;
        zinv[k] = valid ? (ZFAR_ - z[k]) * (1.0f / (ZFAR_ - ZNEAR_)) : 0.0f;
        zmax = fmaxf(zmax, zinv[k]);
    }
    const float delta = fmaxf(__expf((EPS_ - zmax) * (1.0f / GAMMA_)), EPS_);
    float wn[4];
#pragma unroll
    for (int k = 0; k < K_; ++k) wn[k] = prob[k] * __expf((zinv[k] - zmax) * (1.0f / GAMMA_));
    int cl[4];
#pragma unroll
    for (int k = 0; k < K_; ++k) cl[k] = (fidx[k] < 0) ? 0 : fidx[k];
    i32x4 fv[4];
#pragma unroll
    for (int k = 0; k < K_; ++k) fv[k] = *reinterpret_cast<const i32x4*>(faces + 3 * (size_t)cl[k]);
    const f32x4* bp = reinterpret_cast<const f32x4*>(bary + (size_t)p * 12);
    const f32x4 bA = bp[0], bB = bp[1], bC = bp[2];
    const float bb[12] = {bA.x, bA.y, bA.z, bA.w, bB.x, bB.y, bB.z, bB.w, bC.x, bC.y, bC.z, bC.w};
    f32x4 n0[4], n1[4], n2[4];
#pragma unroll
    for (int k = 0; k < K_; ++k) {
        n0[k] = *reinterpret_cast<const f32x4*>(vnorm + 3 * (size_t)fv[k].x);
        n1[k] = *reinterpret_cast<const f32x4*>(vnorm + 3 * (size_t)fv[k].y);
        n2[k] = *reinterpret_cast<const f32x4*>(vnorm + 3 * (size_t)fv[k].z);
    }
    float acc0 = 0.f, acc1 = 0.f, acc2 = 0.f, wsum = 0.f;
#pragma unroll
    for (int k = 0; k < K_; ++k) {
        wsum += wn[k];
        const float b0 = bb[3 * k], b1 = bb[3 * k + 1], b2 = bb[3 * k + 2];
        acc0 += wn[k] * (b0 * n0[k].x + b1 * n1[k].x + b2 * n2[k].x);
        acc1 += wn[k] * (b0 * n0[k].y + b1 * n1[k].y + b2 * n2[k].y);
        acc2 += wn[k] * (b0 * n0[k].z + b1 * n1[k].z + b2 * n2[k].z);
    }
    const float inv_denom = 1.0f / (wsum + delta);
    const float r0 = (acc0 + delta) * inv_denom;
    const float r1 = (acc1 + delta) * inv_denom;
    const float r2 = (acc2 + delta) * inv_denom;
    const float nrm = fmaxf(sqrtf(r0 * r0 + r1 * r1 + r2 * r2), 1e-12f);
    const float inv = 1.0f / nrm;
    float* op = out + (size_t)p * 3;
    op[0] = r0 * inv; op[1] = r1 * inv; op[2] = r2 * inv;
}

extern "C" void kernel_launch(void* const* d_in, const int* in_sizes, int n_in,
                              void* d_out, int out_size, void* d_ws, size_t ws_size,
                              hipStream_t stream) {
    // setup_inputs order: verts(0, unused), vertex_normals(1), bary_coords(2),
    // dists(3), zbuf(4), faces(5), pix_to_face(6)
    const float* vnorm = (const float*)d_in[1];
    const float* bary  = (const float*)d_in[2];
    const float* dists = (const float*)d_in[3];
    const float* zbuf  = (const float*)d_in[4];
    const int*   faces = (const int*)d_in[5];
    const int*   ptf   = (const int*)d_in[6];
    float*       out   = (float*)d_out;

    const int P = N_ * H_ * W_;
    const size_t table_bytes = (size_t)F_ * 16;  // 3.2 MB (16B oct rows)

    if (ws_size >= table_bytes) {
        unsigned int* fnorm = (unsigned int*)d_ws;
        hipLaunchKernelGGL(build_fnorm_kernel,
                           dim3((F_ + 255) / 256), dim3(256), 0, stream,
                           vnorm, faces, fnorm);
        hipLaunchKernelGGL(normal_shader_kernel,
                           dim3(SHADER_BLOCKS), dim3(256), 0, stream,
                           fnorm, bary, dists, zbuf, ptf, out);
    } else {
        hipLaunchKernelGGL(normal_shader_fused_kernel,
                           dim3((P + 255) / 256), dim3(256), 0, stream,
                           vnorm, bary, dists, zbuf, faces, ptf, out, P);
    }
}

// Round 4
// 162.707 us; speedup vs baseline: 1.0107x; 1.0107x over previous
//
#include <hip/hip_runtime.h>
#include <hip/hip_bf16.h>

namespace {
constexpr int N_ = 4, H_ = 512, W_ = 512, K_ = 4;
constexpr int F_ = 200000;
constexpr float SIGMA_ = 1e-4f;
constexpr float GAMMA_ = 1e-4f;
constexpr float EPS_   = 1e-10f;
constexpr float ZNEAR_ = 1.0f, ZFAR_ = 100.0f;

constexpr int P_ = N_ * H_ * W_;          // 1,048,576 pixels
constexpr int SHADER_BLOCKS = P_ / 256;   // 4096 blocks, 1 px/thread
static_assert(P_ % 256 == 0, "grid must tile P exactly");

typedef float        f32x4 __attribute__((ext_vector_type(4), aligned(4)));
typedef int          i32x4 __attribute__((ext_vector_type(4), aligned(4)));
typedef float        f32x3 __attribute__((ext_vector_type(3), aligned(4)));
typedef unsigned int u32x4 __attribute__((ext_vector_type(4), aligned(16)));
} // namespace

// R14 post-mortem of R13: explicit 4-px software pipeline was NEUTRAL (44.6us,
// unchanged) and cost occupancy (35->25%: 1024 blocks = 16 waves/CU, long
// tail). Two structural rewrites with identical timing => compiler already
// extracts the ILP; the binding constraint is wave-level parallelism + the
// ragged one-generation tail (every pipe <25%). Fix: max TLP. 1 px/thread,
// 4096 blocks — hardware keeps 8 blocks/CU resident and REFILLS from the
// queue as waves finish, smoothing the tail. Plus: integer-domain oct decode
// (the 1/32767 scale cancels inside rsqrt since the normal is re-normalized;
// z = 32767-|X|-|Y| is exact integer fp32) — saves 24 VALU muls/pixel.

__device__ __forceinline__ unsigned int oct_encode(float x, float y, float z) {
    const float inv = 1.0f / (fabsf(x) + fabsf(y) + fabsf(z)); // unit input
    const float px = x * inv, py = y * inv, pz = z * inv;
    // Standard octahedral wrap for the z<0 hemisphere: (1-|p.yx|)*sign(p.xy)
    const float wx = (1.0f - fabsf(py)) * copysignf(1.0f, px);
    const float wy = (1.0f - fabsf(px)) * copysignf(1.0f, py);
    const bool neg = pz < 0.0f;
    const float ex = neg ? wx : px;
    const float ey = neg ? wy : py;
    const int ix = (int)rintf(ex * 32767.0f);
    const int iy = (int)rintf(ey * 32767.0f);
    return ((unsigned int)ix & 0xffffu) | (((unsigned int)iy & 0xffffu) << 16);
}

// Integer-domain raw decode: works on the int16 lattice directly. The
// 1/32767 scale cancels in (x,y,z)*rsqrt(x^2+y^2+z^2). For every bit
// pattern the squared norm is > 0 (|X|+|Y|=32767 needed for z==0, which
// forces X,Y not both 0), so inv is always finite.
__device__ __forceinline__ void oct_decode_raw(unsigned int e,
                                               float& x, float& y, float& z,
                                               float& inv) {
    const float X = (float)(short)(unsigned short)(e & 0xffffu);
    const float Y = (float)(short)(unsigned short)(e >> 16);
    z = 32767.0f - fabsf(X) - fabsf(Y);       // exact in fp32 (|val| < 2^17)
    const float t = fmaxf(-z, 0.0f);
    const float xx = X - copysignf(t, X);
    const float yy = Y - copysignf(t, Y);
    x = xx; y = yy;
    inv = rsqrtf(xx * xx + yy * yy + z * z);
}

// K1: fnorm row f (16B): {oct16(n0), oct16(n1), oct16(n2), pad} — written via
// two 8B agent-scope relaxed atomics (write-through; no dirty XCD-L2 lines).
__global__ __launch_bounds__(256) void build_fnorm_kernel(
    const float*  __restrict__ vnorm,
    const int*    __restrict__ faces,
    unsigned int* __restrict__ fnorm)   // [F][4] u32
{
    const int f = blockIdx.x * blockDim.x + threadIdx.x;
    if (f >= F_) return;
    // 16B read covers the 12B face row (4B overread stays in the page).
    const i32x4 fv = *reinterpret_cast<const i32x4*>(faces + 3 * (size_t)f);
    const f32x4 n0 = *reinterpret_cast<const f32x4*>(vnorm + 3 * (size_t)fv.x);
    const f32x4 n1 = *reinterpret_cast<const f32x4*>(vnorm + 3 * (size_t)fv.y);
    const f32x4 n2 = *reinterpret_cast<const f32x4*>(vnorm + 3 * (size_t)fv.z);
    const unsigned long long e0 = oct_encode(n0.x, n0.y, n0.z);
    const unsigned long long e1 = oct_encode(n1.x, n1.y, n1.z);
    const unsigned long long e2 = oct_encode(n2.x, n2.y, n2.z);
    unsigned long long* dst =
        reinterpret_cast<unsigned long long*>(fnorm + (size_t)f * 4);
    __hip_atomic_store(dst + 0, e0 | (e1 << 32), __ATOMIC_RELAXED, __HIP_MEMORY_SCOPE_AGENT);
    __hip_atomic_store(dst + 1, e2,              __ATOMIC_RELAXED, __HIP_MEMORY_SCOPE_AGENT);
}

// K2: 1 px/thread, one-shot with 2x block oversubscription per CU slot —
// hardware refills as waves retire (tail smoothing, max TLP). All streaming
// loads issued first; gathers guarded by max(fidx,0) (ptf-only dependency);
// weight exp-chain overlaps gather latency.
__global__ __launch_bounds__(256) void normal_shader_kernel(
    const unsigned int* __restrict__ fnorm,
    const float*        __restrict__ bary,
    const float*        __restrict__ dists,
    const float*        __restrict__ zbuf,
    const int*          __restrict__ ptf,
    float*              __restrict__ out)
{
    const int p = blockIdx.x * 256 + threadIdx.x;

    // ---- all streaming loads up front (full MLP) ----
    const i32x4 f4 = __builtin_nontemporal_load(reinterpret_cast<const i32x4*>(ptf) + p);
    const f32x4 dv = __builtin_nontemporal_load(reinterpret_cast<const f32x4*>(dists) + p);
    const f32x4 zv = __builtin_nontemporal_load(reinterpret_cast<const f32x4*>(zbuf) + p);
    const f32x4* bp = reinterpret_cast<const f32x4*>(bary + (size_t)p * 12);
    const f32x4 bA = __builtin_nontemporal_load(bp + 0);
    const f32x4 bB = __builtin_nontemporal_load(bp + 1);
    const f32x4 bC = __builtin_nontemporal_load(bp + 2);

    // ---- table gathers (address depends only on ptf, the oldest load) ----
    const int fidx[4] = {f4.x, f4.y, f4.z, f4.w};
    u32x4 row[4];
#pragma unroll
    for (int k = 0; k < K_; ++k) {
        const int r = (fidx[k] < 0) ? 0 : fidx[k];   // only -1 is illegal;
        row[k] = reinterpret_cast<const u32x4*>(fnorm)[r]; // w==0 kills dead slots
    }

    // ---- weights (overlaps gather latency) ----
    const float d[4] = {dv.x, dv.y, dv.z, dv.w};
    const float z[4] = {zv.x, zv.y, zv.z, zv.w};
    float prob[4], zinv[4], zmax = EPS_;
#pragma unroll
    for (int k = 0; k < K_; ++k) {
        const bool valid = fidx[k] >= 0;
        prob[k] = valid ? 1.0f / (1.0f + __expf(d[k] * (1.0f / SIGMA_))) : 0.0f;
        zinv[k] = valid ? (ZFAR_ - z[k]) * (1.0f / (ZFAR_ - ZNEAR_)) : 0.0f;
        zmax = fmaxf(zmax, zinv[k]);
    }
    const float delta = fmaxf(__expf((EPS_ - zmax) * (1.0f / GAMMA_)), EPS_);
    float wn[4];
#pragma unroll
    for (int k = 0; k < K_; ++k)
        wn[k] = prob[k] * __expf((zinv[k] - zmax) * (1.0f / GAMMA_));

    // ---- decode + blend + store ----
    const float bb[12] = {bA.x, bA.y, bA.z, bA.w,
                          bB.x, bB.y, bB.z, bB.w,
                          bC.x, bC.y, bC.z, bC.w};
    float acc0 = 0.f, acc1 = 0.f, acc2 = 0.f, wsum = 0.f;
#pragma unroll
    for (int k = 0; k < K_; ++k) {
        const float w = wn[k];
        wsum += w;
        float x0, y0, z0, i0, x1, y1, z1, i1, x2, y2, z2, i2;
        oct_decode_raw(row[k].x, x0, y0, z0, i0);
        oct_decode_raw(row[k].y, x1, y1, z1, i1);
        oct_decode_raw(row[k].z, x2, y2, z2, i2);
        // fold w * b * (1/|v|) into one scale per normal
        const float s0 = (w * bb[3 * k + 0]) * i0;
        const float s1 = (w * bb[3 * k + 1]) * i1;
        const float s2 = (w * bb[3 * k + 2]) * i2;
        acc0 += s0 * x0 + s1 * x1 + s2 * x2;
        acc1 += s0 * y0 + s1 * y1 + s2 * y2;
        acc2 += s0 * z0 + s1 * z1 + s2 * z2;
    }
    const float inv_denom = 1.0f / (wsum + delta);
    const float r0 = (acc0 + delta) * inv_denom;   // bg = (1,1,1)
    const float r1 = (acc1 + delta) * inv_denom;
    const float r2 = (acc2 + delta) * inv_denom;
    const float nrm = fmaxf(sqrtf(r0 * r0 + r1 * r1 + r2 * r2), 1e-12f);
    const float inv = 1.0f / nrm;
    __builtin_nontemporal_store(
        f32x3{r0 * inv, r1 * inv, r2 * inv},
        reinterpret_cast<f32x3*>(out + (size_t)p * 3));
}

// Fallback (proven R5 structure, exact fp32 path) if ws can't hold the table.
__global__ __launch_bounds__(256) void normal_shader_fused_kernel(
    const float* __restrict__ vnorm,
    const float* __restrict__ bary,
    const float* __restrict__ dists,
    const float* __restrict__ zbuf,
    const int*   __restrict__ faces,
    const int*   __restrict__ ptf,
    float*       __restrict__ out,
    int P)
{
    const int p = blockIdx.x * blockDim.x + threadIdx.x;
    if (p >= P) return;
    const i32x4 f4 = reinterpret_cast<const i32x4*>(ptf)[p];
    const int fidx[4] = {f4.x, f4.y, f4.z, f4.w};
    const f32x4 dv = reinterpret_cast<const f32x4*>(dists)[p];
    const f32x4 zv = reinterpret_cast<const f32x4*>(zbuf)[p];
    const float d[4] = {dv.x, dv.y, dv.z, dv.w};
    const float z[4] = {zv.x, zv.y, zv.z, zv.w};
    float prob[4], zinv[4], zmax = EPS_;
#pragma unroll
    for (int k = 0; k < K_; ++k) {
        const bool valid = fidx[k] >= 0;
        prob[k] = valid ? 1.0f / (1.0f + __expf(d[k] * (1.0f / SIGMA_))) : 0.0f;
        zinv[k] = valid ? (ZFAR_ - z[k]) * (1.0f / (ZFAR_ - ZNEAR_)) : 0.0f;
        zmax = fmaxf(zmax, zinv[k]);
    }
    const float delta = fmaxf(__expf((EPS_ - zmax) * (1.0f / GAMMA_)), EPS_);
    float wn[4];
#pragma unroll
    for (int k = 0; k < K_; ++k) wn[k] = prob[k] * __expf((zinv[k] - zmax) * (1.0f / GAMMA_));
    int cl[4];
#pragma unroll
    for (int k = 0; k < K_; ++k) cl[k] = (fidx[k] < 0) ? 0 : fidx[k];
    i32x4 fv[4];
#pragma unroll
    for (int k = 0; k < K_; ++k) fv[k] = *reinterpret_cast<const i32x4*>(faces + 3 * (size_t)cl[k]);
    const f32x4* bp = reinterpret_cast<const f32x4*>(bary + (size_t)p * 12);
    const f32x4 bA = bp[0], bB = bp[1], bC = bp[2];
    const float bb[12] = {bA.x, bA.y, bA.z, bA.w, bB.x, bB.y, bB.z, bB.w, bC.x, bC.y, bC.z, bC.w};
    f32x4 n0[4], n1[4], n2[4];
#pragma unroll
    for (int k = 0; k < K_; ++k) {
        n0[k] = *reinterpret_cast<const f32x4*>(vnorm + 3 * (size_t)fv[k].x);
        n1[k] = *reinterpret_cast<const f32x4*>(vnorm + 3 * (size_t)fv[k].y);
        n2[k] = *reinterpret_cast<const f32x4*>(vnorm + 3 * (size_t)fv[k].z);
    }
    float acc0 = 0.f, acc1 = 0.f, acc2 = 0.f, wsum = 0.f;
#pragma unroll
    for (int k = 0; k < K_; ++k) {
        wsum += wn[k];
        const float b0 = bb[3 * k], b1 = bb[3 * k + 1], b2 = bb[3 * k + 2];
        acc0 += wn[k] * (b0 * n0[k].x + b1 * n1[k].x + b2 * n2[k].x);
        acc1 += wn[k] * (b0 * n0[k].y + b1 * n1[k].y + b2 * n2[k].y);
        acc2 += wn[k] * (b0 * n0[k].z + b1 * n1[k].z + b2 * n2[k].z);
    }
    const float inv_denom = 1.0f / (wsum + delta);
    const float r0 = (acc0 + delta) * inv_denom;
    const float r1 = (acc1 + delta) * inv_denom;
    const float r2 = (acc2 + delta) * inv_denom;
    const float nrm = fmaxf(sqrtf(r0 * r0 + r1 * r1 + r2 * r2), 1e-12f);
    const float inv = 1.0f / nrm;
    float* op = out + (size_t)p * 3;
    op[0] = r0 * inv; op[1] = r1 * inv; op[2] = r2 * inv;
}

extern "C" void kernel_launch(void* const* d_in, const int* in_sizes, int n_in,
                              void* d_out, int out_size, void* d_ws, size_t ws_size,
                              hipStream_t stream) {
    // setup_inputs order: verts(0, unused), vertex_normals(1), bary_coords(2),
    // dists(3), zbuf(4), faces(5), pix_to_face(6)
    const float* vnorm = (const float*)d_in[1];
    const float* bary  = (const float*)d_in[2];
    const float* dists = (const float*)d_in[3];
    const float* zbuf  = (const float*)d_in[4];
    const int*   faces = (const int*)d_in[5];
    const int*   ptf   = (const int*)d_in[6];
    float*       out   = (float*)d_out;

    const int P = N_ * H_ * W_;
    const size_t table_bytes = (size_t)F_ * 16;  // 3.2 MB (16B oct rows)

    if (ws_size >= table_bytes) {
        unsigned int* fnorm = (unsigned int*)d_ws;
        hipLaunchKernelGGL(build_fnorm_kernel,
                           dim3((F_ + 255) / 256), dim3(256), 0, stream,
                           vnorm, faces, fnorm);
        hipLaunchKernelGGL(normal_shader_kernel,
                           dim3(SHADER_BLOCKS), dim3(256), 0, stream,
                           fnorm, bary, dists, zbuf, ptf, out);
    } else {
        hipLaunchKernelGGL(normal_shader_fused_kernel,
                           dim3((P + 255) / 256), dim3(256), 0, stream,
                           vnorm, bary, dists, zbuf, faces, ptf, out, P);
    }
}

// Round 5
// 152.118 us; speedup vs baseline: 1.0810x; 1.0696x over previous
//
#include <hip/hip_runtime.h>
#include <hip/hip_bf16.h>

namespace {
constexpr int N_ = 4, H_ = 512, W_ = 512, K_ = 4;
constexpr int F_ = 200000;
constexpr float SIGMA_ = 1e-4f;
constexpr float GAMMA_ = 1e-4f;
constexpr float EPS_   = 1e-10f;
constexpr float ZNEAR_ = 1.0f, ZFAR_ = 100.0f;

typedef float        f32x4 __attribute__((ext_vector_type(4), aligned(4)));
typedef int          i32x4 __attribute__((ext_vector_type(4), aligned(4)));
typedef float        f32x3 __attribute__((ext_vector_type(3), aligned(4)));
typedef unsigned int u32x4 __attribute__((ext_vector_type(4), aligned(16)));
} // namespace

// R15 post-mortem ledger:
//   R1: gathers FIRST          -> 48.2us
//   R2/R3/R4: gathers EARLY    -> 44.5us (invariant under 2px/pipeline/1px,
//                                 occupancy 25%->58% with no effect)
//   R0: gathers LATE (wn!=0)   -> <40.6us  (best ever)
// The only variable correlating with duration is gather issue position.
// Theory: the 4 fully-divergent gathers/px (64 lines per instr, L2-cold right
// after K1's write-through) occupy the CU's limited line-fill/MSHR slots for
// an L3/HBM round trip. Issued early they starve the coalesced streaming
// loads' line fills (read BW pinned ~1.7 TB/s irrespective of occupancy).
// Issued late (R0), streams drain at full MSHR availability and the table is
// L2-warm by gather time. Fix: revert to R0's exact structure (2px/thread,
// 2048 blocks, loads -> weights -> wn!=0-guarded addrs -> gathers -> decode),
// keeping only order-neutral VALU trims (integer-domain decode, folded
// w*b*rsqrt scale).

__device__ __forceinline__ unsigned int oct_encode(float x, float y, float z) {
    const float inv = 1.0f / (fabsf(x) + fabsf(y) + fabsf(z)); // unit input
    const float px = x * inv, py = y * inv, pz = z * inv;
    // Standard octahedral wrap for the z<0 hemisphere: (1-|p.yx|)*sign(p.xy)
    const float wx = (1.0f - fabsf(py)) * copysignf(1.0f, px);
    const float wy = (1.0f - fabsf(px)) * copysignf(1.0f, py);
    const bool neg = pz < 0.0f;
    const float ex = neg ? wx : px;
    const float ey = neg ? wy : py;
    const int ix = (int)rintf(ex * 32767.0f);
    const int iy = (int)rintf(ey * 32767.0f);
    return ((unsigned int)ix & 0xffffu) | (((unsigned int)iy & 0xffffu) << 16);
}

// Integer-domain raw decode: works on the int16 lattice directly. The
// 1/32767 scale cancels in (x,y,z)*rsqrt(x^2+y^2+z^2). For every bit
// pattern the squared norm is > 0, so inv is always finite.
__device__ __forceinline__ void oct_decode_raw(unsigned int e,
                                               float& x, float& y, float& z,
                                               float& inv) {
    const float X = (float)(short)(unsigned short)(e & 0xffffu);
    const float Y = (float)(short)(unsigned short)(e >> 16);
    z = 32767.0f - fabsf(X) - fabsf(Y);       // exact in fp32 (|val| < 2^17)
    const float t = fmaxf(-z, 0.0f);
    const float xx = X - copysignf(t, X);
    const float yy = Y - copysignf(t, Y);
    x = xx; y = yy;
    inv = rsqrtf(xx * xx + yy * yy + z * z);
}

// K1: fnorm row f (16B): {oct16(n0), oct16(n1), oct16(n2), pad} — written via
// two 8B agent-scope relaxed atomics (write-through; no dirty XCD-L2 lines).
__global__ __launch_bounds__(256) void build_fnorm_kernel(
    const float*  __restrict__ vnorm,
    const int*    __restrict__ faces,
    unsigned int* __restrict__ fnorm)   // [F][4] u32
{
    const int f = blockIdx.x * blockDim.x + threadIdx.x;
    if (f >= F_) return;
    // 16B read covers the 12B face row (4B overread stays in the page).
    const i32x4 fv = *reinterpret_cast<const i32x4*>(faces + 3 * (size_t)f);
    const f32x4 n0 = *reinterpret_cast<const f32x4*>(vnorm + 3 * (size_t)fv.x);
    const f32x4 n1 = *reinterpret_cast<const f32x4*>(vnorm + 3 * (size_t)fv.y);
    const f32x4 n2 = *reinterpret_cast<const f32x4*>(vnorm + 3 * (size_t)fv.z);
    const unsigned long long e0 = oct_encode(n0.x, n0.y, n0.z);
    const unsigned long long e1 = oct_encode(n1.x, n1.y, n1.z);
    const unsigned long long e2 = oct_encode(n2.x, n2.y, n2.z);
    unsigned long long* dst =
        reinterpret_cast<unsigned long long*>(fnorm + (size_t)f * 4);
    __hip_atomic_store(dst + 0, e0 | (e1 << 32), __ATOMIC_RELAXED, __HIP_MEMORY_SCOPE_AGENT);
    __hip_atomic_store(dst + 1, e2,              __ATOMIC_RELAXED, __HIP_MEMORY_SCOPE_AGENT);
}

// K2: 2 pixels/thread (t, t+P/2) — R0 structure. Phases: (A) all 12 streaming
// loads in flight, (B) weights + wn!=0-guarded gather addresses (gathers
// deliberately LATE so they don't contend with streaming line fills),
// (C) 8 gathers, (D) decode + blend + store.
__global__ __launch_bounds__(256) void normal_shader_kernel(
    const unsigned int* __restrict__ fnorm,
    const float*        __restrict__ bary,
    const float*        __restrict__ dists,
    const float*        __restrict__ zbuf,
    const int*          __restrict__ ptf,
    float*              __restrict__ out,
    int P)
{
    const int t = blockIdx.x * blockDim.x + threadIdx.x;
    const int halfP = P >> 1;
    if (t >= halfP) return;
    const int pp[2] = {t, t + halfP};

    // ---- Phase A: all streaming loads for both pixels (independent) ----
    i32x4 f4[2]; f32x4 dv[2], zv[2], bA[2], bB[2], bC[2];
#pragma unroll
    for (int j = 0; j < 2; ++j) {
        const int p = pp[j];
        f4[j] = __builtin_nontemporal_load(reinterpret_cast<const i32x4*>(ptf) + p);
        dv[j] = __builtin_nontemporal_load(reinterpret_cast<const f32x4*>(dists) + p);
        zv[j] = __builtin_nontemporal_load(reinterpret_cast<const f32x4*>(zbuf) + p);
        const f32x4* bp = reinterpret_cast<const f32x4*>(bary + (size_t)p * 12);
        bA[j] = __builtin_nontemporal_load(bp + 0);
        bB[j] = __builtin_nontemporal_load(bp + 1);
        bC[j] = __builtin_nontemporal_load(bp + 2);
    }

    // ---- Phase B: weights + gather addresses (wn!=0 guard => gathers late) ----
    float wn[2][4], delta[2];
    const u32x4* rp[2][4];
#pragma unroll
    for (int j = 0; j < 2; ++j) {
        const int fidx[4] = {f4[j].x, f4[j].y, f4[j].z, f4[j].w};
        const float d[4] = {dv[j].x, dv[j].y, dv[j].z, dv[j].w};
        const float z[4] = {zv[j].x, zv[j].y, zv[j].z, zv[j].w};
        float prob[4], zinv[4], zmax = EPS_;
#pragma unroll
        for (int k = 0; k < K_; ++k) {
            const bool valid = fidx[k] >= 0;
            prob[k] = valid ? 1.0f / (1.0f + __expf(d[k] * (1.0f / SIGMA_))) : 0.0f;
            zinv[k] = valid ? (ZFAR_ - z[k]) * (1.0f / (ZFAR_ - ZNEAR_)) : 0.0f;
            zmax = fmaxf(zmax, zinv[k]);
        }
        delta[j] = fmaxf(__expf((EPS_ - zmax) * (1.0f / GAMMA_)), EPS_);
#pragma unroll
        for (int k = 0; k < K_; ++k) {
            wn[j][k] = prob[k] * __expf((zinv[k] - zmax) * (1.0f / GAMMA_));
            rp[j][k] = reinterpret_cast<const u32x4*>(fnorm) +
                       ((wn[j][k] != 0.0f) ? fidx[k] : 0);
        }
    }

    // ---- Phase C: all 8 slot gathers in flight (16B each) ----
    u32x4 row[2][4];
#pragma unroll
    for (int j = 0; j < 2; ++j)
#pragma unroll
        for (int k = 0; k < K_; ++k)
            row[j][k] = *rp[j][k];

    // ---- Phase D: decode + blend + store ----
#pragma unroll
    for (int j = 0; j < 2; ++j) {
        const float bb[12] = {bA[j].x, bA[j].y, bA[j].z, bA[j].w,
                              bB[j].x, bB[j].y, bB[j].z, bB[j].w,
                              bC[j].x, bC[j].y, bC[j].z, bC[j].w};
        float acc0 = 0.f, acc1 = 0.f, acc2 = 0.f, wsum = 0.f;
#pragma unroll
        for (int k = 0; k < K_; ++k) {
            const float w = wn[j][k];
            wsum += w;
            float x0, y0, z0, i0, x1, y1, z1, i1, x2, y2, z2, i2;
            oct_decode_raw(row[j][k].x, x0, y0, z0, i0);
            oct_decode_raw(row[j][k].y, x1, y1, z1, i1);
            oct_decode_raw(row[j][k].z, x2, y2, z2, i2);
            // fold w * b * (1/|v|) into one scale per normal
            const float s0 = (w * bb[3 * k + 0]) * i0;
            const float s1 = (w * bb[3 * k + 1]) * i1;
            const float s2 = (w * bb[3 * k + 2]) * i2;
            acc0 += s0 * x0 + s1 * x1 + s2 * x2;
            acc1 += s0 * y0 + s1 * y1 + s2 * y2;
            acc2 += s0 * z0 + s1 * z1 + s2 * z2;
        }
        const float inv_denom = 1.0f / (wsum + delta[j]);
        const float r0 = (acc0 + delta[j]) * inv_denom;   // bg = (1,1,1)
        const float r1 = (acc1 + delta[j]) * inv_denom;
        const float r2 = (acc2 + delta[j]) * inv_denom;
        const float nrm = fmaxf(sqrtf(r0 * r0 + r1 * r1 + r2 * r2), 1e-12f);
        const float inv = 1.0f / nrm;
        __builtin_nontemporal_store(
            f32x3{r0 * inv, r1 * inv, r2 * inv},
            reinterpret_cast<f32x3*>(out + (size_t)pp[j] * 3));
    }
}

// Fallback (proven R5 structure, exact fp32 path) if ws can't hold the table.
__global__ __launch_bounds__(256) void normal_shader_fused_kernel(
    const float* __restrict__ vnorm,
    const float* __restrict__ bary,
    const float* __restrict__ dists,
    const float* __restrict__ zbuf,
    const int*   __restrict__ faces,
    const int*   __restrict__ ptf,
    float*       __restrict__ out,
    int P)
{
    const int p = blockIdx.x * blockDim.x + threadIdx.x;
    if (p >= P) return;
    const i32x4 f4 = reinterpret_cast<const i32x4*>(ptf)[p];
    const int fidx[4] = {f4.x, f4.y, f4.z, f4.w};
    const f32x4 dv = reinterpret_cast<const f32x4*>(dists)[p];
    const f32x4 zv = reinterpret_cast<const f32x4*>(zbuf)[p];
    const float d[4] = {dv.x, dv.y, dv.z, dv.w};
    const float z[4] = {zv.x, zv.y, zv.z, zv.w};
    float prob[4], zinv[4], zmax = EPS_;
#pragma unroll
    for (int k = 0; k < K_; ++k) {
        const bool valid = fidx[k] >= 0;
        prob[k] = valid ? 1.0f / (1.0f + __expf(d[k] * (1.0f / SIGMA_))) : 0.0f;
        zinv[k] = valid ? (ZFAR_ - z[k]) * (1.0f / (ZFAR_ - ZNEAR_)) : 0.0f;
        zmax = fmaxf(zmax, zinv[k]);
    }
    const float delta = fmaxf(__expf((EPS_ - zmax) * (1.0f / GAMMA_)), EPS_);
    float wn[4];
#pragma unroll
    for (int k = 0; k < K_; ++k) wn[k] = prob[k] * __expf((zinv[k] - zmax) * (1.0f / GAMMA_));
    int cl[4];
#pragma unroll
    for (int k = 0; k < K_; ++k) cl[k] = (wn[k] != 0.0f) ? fidx[k] : 0;
    i32x4 fv[4];
#pragma unroll
    for (int k = 0; k < K_; ++k) fv[k] = *reinterpret_cast<const i32x4*>(faces + 3 * (size_t)cl[k]);
    const f32x4* bp = reinterpret_cast<const f32x4*>(bary + (size_t)p * 12);
    const f32x4 bA = bp[0], bB = bp[1], bC = bp[2];
    const float bb[12] = {bA.x, bA.y, bA.z, bA.w, bB.x, bB.y, bB.z, bB.w, bC.x, bC.y, bC.z, bC.w};
    f32x4 n0[4], n1[4], n2[4];
#pragma unroll
    for (int k = 0; k < K_; ++k) {
        n0[k] = *reinterpret_cast<const f32x4*>(vnorm + 3 * (size_t)fv[k].x);
        n1[k] = *reinterpret_cast<const f32x4*>(vnorm + 3 * (size_t)fv[k].y);
        n2[k] = *reinterpret_cast<const f32x4*>(vnorm + 3 * (size_t)fv[k].z);
    }
    float acc0 = 0.f, acc1 = 0.f, acc2 = 0.f, wsum = 0.f;
#pragma unroll
    for (int k = 0; k < K_; ++k) {
        wsum += wn[k];
        const float b0 = bb[3 * k], b1 = bb[3 * k + 1], b2 = bb[3 * k + 2];
        acc0 += wn[k] * (b0 * n0[k].x + b1 * n1[k].x + b2 * n2[k].x);
        acc1 += wn[k] * (b0 * n0[k].y + b1 * n1[k].y + b2 * n2[k].y);
        acc2 += wn[k] * (b0 * n0[k].z + b1 * n1[k].z + b2 * n2[k].z);
    }
    const float inv_denom = 1.0f / (wsum + delta);
    const float r0 = (acc0 + delta) * inv_denom;
    const float r1 = (acc1 + delta) * inv_denom;
    const float r2 = (acc2 + delta) * inv_denom;
    const float nrm = fmaxf(sqrtf(r0 * r0 + r1 * r1 + r2 * r2), 1e-12f);
    const float inv = 1.0f / nrm;
    float* op = out + (size_t)p * 3;
    op[0] = r0 * inv; op[1] = r1 * inv; op[2] = r2 * inv;
}

extern "C" void kernel_launch(void* const* d_in, const int* in_sizes, int n_in,
                              void* d_out, int out_size, void* d_ws, size_t ws_size,
                              hipStream_t stream) {
    // setup_inputs order: verts(0, unused), vertex_normals(1), bary_coords(2),
    // dists(3), zbuf(4), faces(5), pix_to_face(6)
    const float* vnorm = (const float*)d_in[1];
    const float* bary  = (const float*)d_in[2];
    const float* dists = (const float*)d_in[3];
    const float* zbuf  = (const float*)d_in[4];
    const int*   faces = (const int*)d_in[5];
    const int*   ptf   = (const int*)d_in[6];
    float*       out   = (float*)d_out;

    const int P = N_ * H_ * W_;
    const size_t table_bytes = (size_t)F_ * 16;  // 3.2 MB (16B oct rows)

    if (ws_size >= table_bytes) {
        unsigned int* fnorm = (unsigned int*)d_ws;
        hipLaunchKernelGGL(build_fnorm_kernel,
                           dim3((F_ + 255) / 256), dim3(256), 0, stream,
                           vnorm, faces, fnorm);
        hipLaunchKernelGGL(normal_shader_kernel,
                           dim3(((P >> 1) + 255) / 256), dim3(256), 0, stream,
                           fnorm, bary, dists, zbuf, ptf, out, P);
    } else {
        hipLaunchKernelGGL(normal_shader_fused_kernel,
                           dim3((P + 255) / 256), dim3(256), 0, stream,
                           vnorm, bary, dists, zbuf, faces, ptf, out, P);
    }
}

// Round 6
// 148.911 us; speedup vs baseline: 1.1043x; 1.0215x over previous
//
#include <hip/hip_runtime.h>
#include <hip/hip_bf16.h>

namespace {
constexpr int N_ = 4, H_ = 512, W_ = 512, K_ = 4;
constexpr int F_ = 200000;
constexpr float SIGMA_ = 1e-4f;
constexpr float GAMMA_ = 1e-4f;
constexpr float EPS_   = 1e-10f;
constexpr float ZNEAR_ = 1.0f, ZFAR_ = 100.0f;

typedef float        f32x4 __attribute__((ext_vector_type(4), aligned(4)));
typedef int          i32x4 __attribute__((ext_vector_type(4), aligned(4)));
typedef float        f32x3 __attribute__((ext_vector_type(3), aligned(4)));
typedef unsigned int u32x4 __attribute__((ext_vector_type(4), aligned(16)));
} // namespace

// R16. Ledger: gathers FIRST 48.2 / EARLY 44.5 (invariant under ILP, SW
// pipeline, 2x occupancy) / LATE (wn!=0 guard) <40.4 — best. Refined
// mechanism: GAMMA=1e-4 makes exp((zinv-zmax)/GAMMA) underflow to exact 0
// for any slot >~0.01 below the max, so ~97% of pixels have exactly ONE
// live slot; the wn!=0 guard redirects ~3/4 of gathers to row 0 (broadcast,
// free) — gathers-late is a 4x divergent-gather reduction, not a scheduling
// trick. This round's single variable: REMOVE the nontemporal hints from the
// 6 streaming loads (keep NT store). Read BW has been pinned at ~1.8 TB/s
// across every structure while pure streams hit 6.3 TB/s on this machine;
// NT (slc/nt, no L2 allocation) is the one untested difference between our
// streams and the fast ones. Everything else byte-identical to R5.

__device__ __forceinline__ unsigned int oct_encode(float x, float y, float z) {
    const float inv = 1.0f / (fabsf(x) + fabsf(y) + fabsf(z)); // unit input
    const float px = x * inv, py = y * inv, pz = z * inv;
    // Standard octahedral wrap for the z<0 hemisphere: (1-|p.yx|)*sign(p.xy)
    const float wx = (1.0f - fabsf(py)) * copysignf(1.0f, px);
    const float wy = (1.0f - fabsf(px)) * copysignf(1.0f, py);
    const bool neg = pz < 0.0f;
    const float ex = neg ? wx : px;
    const float ey = neg ? wy : py;
    const int ix = (int)rintf(ex * 32767.0f);
    const int iy = (int)rintf(ey * 32767.0f);
    return ((unsigned int)ix & 0xffffu) | (((unsigned int)iy & 0xffffu) << 16);
}

// Integer-domain raw decode: works on the int16 lattice directly. The
// 1/32767 scale cancels in (x,y,z)*rsqrt(x^2+y^2+z^2). For every bit
// pattern the squared norm is > 0, so inv is always finite.
__device__ __forceinline__ void oct_decode_raw(unsigned int e,
                                               float& x, float& y, float& z,
                                               float& inv) {
    const float X = (float)(short)(unsigned short)(e & 0xffffu);
    const float Y = (float)(short)(unsigned short)(e >> 16);
    z = 32767.0f - fabsf(X) - fabsf(Y);       // exact in fp32 (|val| < 2^17)
    const float t = fmaxf(-z, 0.0f);
    const float xx = X - copysignf(t, X);
    const float yy = Y - copysignf(t, Y);
    x = xx; y = yy;
    inv = rsqrtf(xx * xx + yy * yy + z * z);
}

// K1: fnorm row f (16B): {oct16(n0), oct16(n1), oct16(n2), pad} — written via
// two 8B agent-scope relaxed atomics (write-through; no dirty XCD-L2 lines).
__global__ __launch_bounds__(256) void build_fnorm_kernel(
    const float*  __restrict__ vnorm,
    const int*    __restrict__ faces,
    unsigned int* __restrict__ fnorm)   // [F][4] u32
{
    const int f = blockIdx.x * blockDim.x + threadIdx.x;
    if (f >= F_) return;
    // 16B read covers the 12B face row (4B overread stays in the page).
    const i32x4 fv = *reinterpret_cast<const i32x4*>(faces + 3 * (size_t)f);
    const f32x4 n0 = *reinterpret_cast<const f32x4*>(vnorm + 3 * (size_t)fv.x);
    const f32x4 n1 = *reinterpret_cast<const f32x4*>(vnorm + 3 * (size_t)fv.y);
    const f32x4 n2 = *reinterpret_cast<const f32x4*>(vnorm + 3 * (size_t)fv.z);
    const unsigned long long e0 = oct_encode(n0.x, n0.y, n0.z);
    const unsigned long long e1 = oct_encode(n1.x, n1.y, n1.z);
    const unsigned long long e2 = oct_encode(n2.x, n2.y, n2.z);
    unsigned long long* dst =
        reinterpret_cast<unsigned long long*>(fnorm + (size_t)f * 4);
    __hip_atomic_store(dst + 0, e0 | (e1 << 32), __ATOMIC_RELAXED, __HIP_MEMORY_SCOPE_AGENT);
    __hip_atomic_store(dst + 1, e2,              __ATOMIC_RELAXED, __HIP_MEMORY_SCOPE_AGENT);
}

// K2: 2 pixels/thread (t, t+P/2) — R0 structure. Phases: (A) all 12 streaming
// loads in flight (PLAIN loads this round), (B) weights + wn!=0-guarded
// gather addresses (gathers deliberately LATE: ~97% of slots are dead via
// exp underflow and collapse to a free row-0 broadcast), (C) 8 gathers,
// (D) decode + blend + store.
__global__ __launch_bounds__(256) void normal_shader_kernel(
    const unsigned int* __restrict__ fnorm,
    const float*        __restrict__ bary,
    const float*        __restrict__ dists,
    const float*        __restrict__ zbuf,
    const int*          __restrict__ ptf,
    float*              __restrict__ out,
    int P)
{
    const int t = blockIdx.x * blockDim.x + threadIdx.x;
    const int halfP = P >> 1;
    if (t >= halfP) return;
    const int pp[2] = {t, t + halfP};

    // ---- Phase A: all streaming loads for both pixels (independent) ----
    i32x4 f4[2]; f32x4 dv[2], zv[2], bA[2], bB[2], bC[2];
#pragma unroll
    for (int j = 0; j < 2; ++j) {
        const int p = pp[j];
        f4[j] = reinterpret_cast<const i32x4*>(ptf)[p];
        dv[j] = reinterpret_cast<const f32x4*>(dists)[p];
        zv[j] = reinterpret_cast<const f32x4*>(zbuf)[p];
        const f32x4* bp = reinterpret_cast<const f32x4*>(bary + (size_t)p * 12);
        bA[j] = bp[0];
        bB[j] = bp[1];
        bC[j] = bp[2];
    }

    // ---- Phase B: weights + gather addresses (wn!=0 guard => gathers late) ----
    float wn[2][4], delta[2];
    const u32x4* rp[2][4];
#pragma unroll
    for (int j = 0; j < 2; ++j) {
        const int fidx[4] = {f4[j].x, f4[j].y, f4[j].z, f4[j].w};
        const float d[4] = {dv[j].x, dv[j].y, dv[j].z, dv[j].w};
        const float z[4] = {zv[j].x, zv[j].y, zv[j].z, zv[j].w};
        float prob[4], zinv[4], zmax = EPS_;
#pragma unroll
        for (int k = 0; k < K_; ++k) {
            const bool valid = fidx[k] >= 0;
            prob[k] = valid ? 1.0f / (1.0f + __expf(d[k] * (1.0f / SIGMA_))) : 0.0f;
            zinv[k] = valid ? (ZFAR_ - z[k]) * (1.0f / (ZFAR_ - ZNEAR_)) : 0.0f;
            zmax = fmaxf(zmax, zinv[k]);
        }
        delta[j] = fmaxf(__expf((EPS_ - zmax) * (1.0f / GAMMA_)), EPS_);
#pragma unroll
        for (int k = 0; k < K_; ++k) {
            wn[j][k] = prob[k] * __expf((zinv[k] - zmax) * (1.0f / GAMMA_));
            rp[j][k] = reinterpret_cast<const u32x4*>(fnorm) +
                       ((wn[j][k] != 0.0f) ? fidx[k] : 0);
        }
    }

    // ---- Phase C: all 8 slot gathers in flight (16B each) ----
    u32x4 row[2][4];
#pragma unroll
    for (int j = 0; j < 2; ++j)
#pragma unroll
        for (int k = 0; k < K_; ++k)
            row[j][k] = *rp[j][k];

    // ---- Phase D: decode + blend + store ----
#pragma unroll
    for (int j = 0; j < 2; ++j) {
        const float bb[12] = {bA[j].x, bA[j].y, bA[j].z, bA[j].w,
                              bB[j].x, bB[j].y, bB[j].z, bB[j].w,
                              bC[j].x, bC[j].y, bC[j].z, bC[j].w};
        float acc0 = 0.f, acc1 = 0.f, acc2 = 0.f, wsum = 0.f;
#pragma unroll
        for (int k = 0; k < K_; ++k) {
            const float w = wn[j][k];
            wsum += w;
            float x0, y0, z0, i0, x1, y1, z1, i1, x2, y2, z2, i2;
            oct_decode_raw(row[j][k].x, x0, y0, z0, i0);
            oct_decode_raw(row[j][k].y, x1, y1, z1, i1);
            oct_decode_raw(row[j][k].z, x2, y2, z2, i2);
            // fold w * b * (1/|v|) into one scale per normal
            const float s0 = (w * bb[3 * k + 0]) * i0;
            const float s1 = (w * bb[3 * k + 1]) * i1;
            const float s2 = (w * bb[3 * k + 2]) * i2;
            acc0 += s0 * x0 + s1 * x1 + s2 * x2;
            acc1 += s0 * y0 + s1 * y1 + s2 * y2;
            acc2 += s0 * z0 + s1 * z1 + s2 * z2;
        }
        const float inv_denom = 1.0f / (wsum + delta[j]);
        const float r0 = (acc0 + delta[j]) * inv_denom;   // bg = (1,1,1)
        const float r1 = (acc1 + delta[j]) * inv_denom;
        const float r2 = (acc2 + delta[j]) * inv_denom;
        const float nrm = fmaxf(sqrtf(r0 * r0 + r1 * r1 + r2 * r2), 1e-12f);
        const float inv = 1.0f / nrm;
        __builtin_nontemporal_store(
            f32x3{r0 * inv, r1 * inv, r2 * inv},
            reinterpret_cast<f32x3*>(out + (size_t)pp[j] * 3));
    }
}

// Fallback (proven R5 structure, exact fp32 path) if ws can't hold the table.
__global__ __launch_bounds__(256) void normal_shader_fused_kernel(
    const float* __restrict__ vnorm,
    const float* __restrict__ bary,
    const float* __restrict__ dists,
    const float* __restrict__ zbuf,
    const int*   __restrict__ faces,
    const int*   __restrict__ ptf,
    float*       __restrict__ out,
    int P)
{
    const int p = blockIdx.x * blockDim.x + threadIdx.x;
    if (p >= P) return;
    const i32x4 f4 = reinterpret_cast<const i32x4*>(ptf)[p];
    const int fidx[4] = {f4.x, f4.y, f4.z, f4.w};
    const f32x4 dv = reinterpret_cast<const f32x4*>(dists)[p];
    const f32x4 zv = reinterpret_cast<const f32x4*>(zbuf)[p];
    const float d[4] = {dv.x, dv.y, dv.z, dv.w};
    const float z[4] = {zv.x, zv.y, zv.z, zv.w};
    float prob[4], zinv[4], zmax = EPS_;
#pragma unroll
    for (int k = 0; k < K_; ++k) {
        const bool valid = fidx[k] >= 0;
        prob[k] = valid ? 1.0f / (1.0f + __expf(d[k] * (1.0f / SIGMA_))) : 0.0f;
        zinv[k] = valid ? (ZFAR_ - z[k]) * (1.0f / (ZFAR_ - ZNEAR_)) : 0.0f;
        zmax = fmaxf(zmax, zinv[k]);
    }
    const float delta = fmaxf(__expf((EPS_ - zmax) * (1.0f / GAMMA_)), EPS_);
    float wn[4];
#pragma unroll
    for (int k = 0; k < K_; ++k) wn[k] = prob[k] * __expf((zinv[k] - zmax) * (1.0f / GAMMA_));
    int cl[4];
#pragma unroll
    for (int k = 0; k < K_; ++k) cl[k] = (wn[k] != 0.0f) ? fidx[k] : 0;
    i32x4 fv[4];
#pragma unroll
    for (int k = 0; k < K_; ++k) fv[k] = *reinterpret_cast<const i32x4*>(faces + 3 * (size_t)cl[k]);
    const f32x4* bp = reinterpret_cast<const f32x4*>(bary + (size_t)p * 12);
    const f32x4 bA = bp[0], bB = bp[1], bC = bp[2];
    const float bb[12] = {bA.x, bA.y, bA.z, bA.w, bB.x, bB.y, bB.z, bB.w, bC.x, bC.y, bC.z, bC.w};
    f32x4 n0[4], n1[4], n2[4];
#pragma unroll
    for (int k = 0; k < K_; ++k) {
        n0[k] = *reinterpret_cast<const f32x4*>(vnorm + 3 * (size_t)fv[k].x);
        n1[k] = *reinterpret_cast<const f32x4*>(vnorm + 3 * (size_t)fv[k].y);
        n2[k] = *reinterpret_cast<const f32x4*>(vnorm + 3 * (size_t)fv[k].z);
    }
    float acc0 = 0.f, acc1 = 0.f, acc2 = 0.f, wsum = 0.f;
#pragma unroll
    for (int k = 0; k < K_; ++k) {
        wsum += wn[k];
        const float b0 = bb[3 * k], b1 = bb[3 * k + 1], b2 = bb[3 * k + 2];
        acc0 += wn[k] * (b0 * n0[k].x + b1 * n1[k].x + b2 * n2[k].x);
        acc1 += wn[k] * (b0 * n0[k].y + b1 * n1[k].y + b2 * n2[k].y);
        acc2 += wn[k] * (b0 * n0[k].z + b1 * n1[k].z + b2 * n2[k].z);
    }
    const float inv_denom = 1.0f / (wsum + delta);
    const float r0 = (acc0 + delta) * inv_denom;
    const float r1 = (acc1 + delta) * inv_denom;
    const float r2 = (acc2 + delta) * inv_denom;
    const float nrm = fmaxf(sqrtf(r0 * r0 + r1 * r1 + r2 * r2), 1e-12f);
    const float inv = 1.0f / nrm;
    float* op = out + (size_t)p * 3;
    op[0] = r0 * inv; op[1] = r1 * inv; op[2] = r2 * inv;
}

extern "C" void kernel_launch(void* const* d_in, const int* in_sizes, int n_in,
                              void* d_out, int out_size, void* d_ws, size_t ws_size,
                              hipStream_t stream) {
    // setup_inputs order: verts(0, unused), vertex_normals(1), bary_coords(2),
    // dists(3), zbuf(4), faces(5), pix_to_face(6)
    const float* vnorm = (const float*)d_in[1];
    const float* bary  = (const float*)d_in[2];
    const float* dists = (const float*)d_in[3];
    const float* zbuf  = (const float*)d_in[4];
    const int*   faces = (const int*)d_in[5];
    const int*   ptf   = (const int*)d_in[6];
    float*       out   = (float*)d_out;

    const int P = N_ * H_ * W_;
    const size_t table_bytes = (size_t)F_ * 16;  // 3.2 MB (16B oct rows)

    if (ws_size >= table_bytes) {
        unsigned int* fnorm = (unsigned int*)d_ws;
        hipLaunchKernelGGL(build_fnorm_kernel,
                           dim3((F_ + 255) / 256), dim3(256), 0, stream,
                           vnorm, faces, fnorm);
        hipLaunchKernelGGL(normal_shader_kernel,
                           dim3(((P >> 1) + 255) / 256), dim3(256), 0, stream,
                           fnorm, bary, dists, zbuf, ptf, out, P);
    } else {
        hipLaunchKernelGGL(normal_shader_fused_kernel,
                           dim3((P + 255) / 256), dim3(256), 0, stream,
                           vnorm, bary, dists, zbuf, faces, ptf, out, P);
    }
}